// Round 3
// baseline (239.633 us; speedup 1.0000x reference)
//
#include <hip/hip_runtime.h>
#include <hip/hip_bf16.h>
#include <math.h>

// Problem constants (fixed by setup_inputs)
#define NN   5570
#define BB   16
#define CIN  35
#define NJ   16        // (d,j): d in [0,4), j in [0,4) (j: gate-o2, gate-o3, upd-o0, upd-o1)
#define COLS 256       // BB * NJ
#define MPAD 5632      // NN padded to 88*64
#define OUTER 8        // split-K slices
#define KW   704       // MPAD/OUTER, 22 steps of 32

// workspace layout (float offsets); total = 7,895,552 floats = 31.6 MB
#define OFF_RSUM 0                                          // [OUTER][MPAD] fp32
#define OFF_G0   45056                                      // [BB][NN][NJ] fp32
#define OFF_PGU  1470976                                    // [OUTER][BB][NN][NJ] bf16
#define OFF_GT   (OFF_PGU + (size_t)OUTER*BB*NN*NJ/2)       // [COLS][MPAD] bf16

typedef __attribute__((ext_vector_type(8))) short  short8;
typedef __attribute__((ext_vector_type(4))) float  floatx4;

static __device__ inline ushort f2bf(float f) {
    union { __hip_bfloat16 h; ushort u; } cv;
    cv.h = __float2bfloat16(f);
    return cv.u;
}

// ---------------------------------------------------------------------------
// Kernel G: per (b, m):
//   a0[dj] = sum_c x[b,m,c] * w_k0[d,c,j]  -> g0  fp32 [b][m][16]
//   a1[dj] = sum_c x[b,m,c] * w_k1[d,c,j]  -> GT  bf16 [b*16+dj][m]  (transposed)
// tail m in [NN, MPAD): GT <- 0
// ---------------------------------------------------------------------------
__global__ __launch_bounds__(256)
void kg_g(const float* __restrict__ x, const float* __restrict__ wg,
          const float* __restrict__ wu, float* __restrict__ g0,
          ushort* __restrict__ gtu) {
    __shared__ float xs[256 * CIN];
    __shared__ float wl[8 * CIN * 4];   // [(k*4+d)*35 + c]*4 + j
    int tid = threadIdx.x;
    int b   = blockIdx.y;
    int m0  = blockIdx.x * 256;

    for (int i = tid; i < 8 * CIN * 4; i += 256) {
        int j = i & 3, rest = i >> 2;
        int c = rest % CIN, kd = rest / CIN;
        int k = kd >> 2, d = kd & 3;
        float v;
        if (j < 2) v = wg[((d * 2 + k) * 37 + c) * 4 + 2 + j];
        else       v = wu[((d * 2 + k) * 37 + c) * 2 + (j - 2)];
        wl[i] = v;
    }
    int rows = NN - m0; if (rows > 256) rows = 256; if (rows < 0) rows = 0;
    const float* xsrc = x + ((size_t)b * NN + m0) * CIN;
    for (int i = tid; i < rows * CIN; i += 256) xs[i] = xsrc[i];
    __syncthreads();

    float a0[16], a1[16];
    #pragma unroll
    for (int i = 0; i < 16; ++i) { a0[i] = 0.f; a1[i] = 0.f; }

    int m = m0 + tid;
    if (m < NN) {
        for (int c = 0; c < CIN; ++c) {
            float xa = xs[tid * CIN + c];
            #pragma unroll
            for (int kd = 0; kd < 8; ++kd) {
                const float4 w = *(const float4*)&wl[(kd * CIN + c) * 4];
                const int d4 = (kd & 3) * 4;
                if (kd < 4) {
                    a0[d4+0] += xa*w.x; a0[d4+1] += xa*w.y;
                    a0[d4+2] += xa*w.z; a0[d4+3] += xa*w.w;
                } else {
                    a1[d4+0] += xa*w.x; a1[d4+1] += xa*w.y;
                    a1[d4+2] += xa*w.z; a1[d4+3] += xa*w.w;
                }
            }
        }
        float* p0 = g0 + ((size_t)b * NN + m) * NJ;
        ((float4*)p0)[0] = make_float4(a0[0], a0[1], a0[2], a0[3]);
        ((float4*)p0)[1] = make_float4(a0[4], a0[5], a0[6], a0[7]);
        ((float4*)p0)[2] = make_float4(a0[8], a0[9], a0[10], a0[11]);
        ((float4*)p0)[3] = make_float4(a0[12], a0[13], a0[14], a0[15]);
        #pragma unroll
        for (int dj = 0; dj < 16; ++dj)
            gtu[(size_t)(b * 16 + dj) * MPAD + m] = f2bf(a1[dj]);
    } else {
        #pragma unroll
        for (int dj = 0; dj < 16; ++dj)
            gtu[(size_t)(b * 16 + dj) * MPAD + m] = 0;
    }
}

// ---------------------------------------------------------------------------
// Kernel B (MFMA, barrier-free, zero LDS):
//   PG[s][b][n][dj] = sum_{m in slice s} exp(relu(E_n.E_m)) * G1[m][b*16+dj]
//   rsum[s][n]      = sum_{m in slice s} exp(relu(E_n.E_m))
// Block = 4 waves; wave w owns rows n0 = bx*64 + w*16 (one 16-row tile) and
// ALL 16 col-tiles (col-tile ct == batch ct since NJ==16). Scores are computed
// straight into the MFMA A-fragment registers: lane holds A[n0+(l&15)][quad*8+u].
// No __syncthreads anywhere; B-fragments stream from L1/L2 (gtu is 2.9 MB).
// ---------------------------------------------------------------------------
template <bool CHECK>
static __device__ inline void kb_body(const float4* __restrict__ E4,
                                      const ushort* __restrict__ gbase,
                                      const float4 en, int k0,
                                      floatx4 (&acc)[16], float& rowsum,
                                      int quad) {
    #pragma unroll 11
    for (int step = 0; step < KW / 32; ++step) {
        const int mq = k0 + step * 32 + quad * 8;
        short8 afrag;
        #pragma unroll
        for (int u = 0; u < 8; ++u) {
            int m = mq + u;
            float4 em = E4[(CHECK && m >= NN) ? 0 : m];
            float dt = en.x*em.x + en.y*em.y + en.z*em.z + en.w*em.w;
            float sv = __expf(fmaxf(dt, 0.f));
            if (CHECK && m >= NN) sv = 0.f;
            rowsum += sv;
            afrag[u] = (short)f2bf(sv);
        }
        #pragma unroll
        for (int ct = 0; ct < 16; ++ct) {
            short8 bf = *(const short8*)&gbase[(size_t)ct * 16 * MPAD + mq];
            acc[ct] = __builtin_amdgcn_mfma_f32_16x16x32_bf16(afrag, bf, acc[ct], 0, 0, 0);
        }
    }
}

__global__ __launch_bounds__(256)
void kb_pg(const float* __restrict__ e, const ushort* __restrict__ gtu,
           ushort* __restrict__ pgu, float* __restrict__ rsum) {
    const int tid  = threadIdx.x;
    const int wave = tid >> 6;
    const int lane = tid & 63;
    const int l15  = lane & 15;
    const int quad = lane >> 4;
    const int n0   = blockIdx.x * 64 + wave * 16;
    const int s    = blockIdx.y;
    const int k0   = s * KW;
    const float4* E4 = (const float4*)e;

    const int nr = n0 + l15;
    const float4 en = E4[nr < NN ? nr : 0];

    floatx4 acc[16];
    #pragma unroll
    for (int i = 0; i < 16; ++i) acc[i] = (floatx4){0.f, 0.f, 0.f, 0.f};
    float rowsum = 0.f;

    const ushort* gbase = gtu + (size_t)l15 * MPAD;

    if (k0 + KW <= NN) kb_body<false>(E4, gbase, en, k0, acc, rowsum, quad);
    else               kb_body<true >(E4, gbase, en, k0, acc, rowsum, quad);

    // rowsum for row nr lives in lanes {l15, l15+16, l15+32, l15+48}
    rowsum += __shfl_xor(rowsum, 16);
    rowsum += __shfl_xor(rowsum, 32);
    if (quad == 0 && nr < NN) rsum[(size_t)s * MPAD + nr] = rowsum;

    // store PG bf16: D[row = quad*4 + j][col = l15]; col-tile ct == batch index
    #pragma unroll
    for (int ct = 0; ct < 16; ++ct) {
        ushort* dst = pgu + ((size_t)s * BB + ct) * NN * NJ + l15;
        #pragma unroll
        for (int j = 0; j < 4; ++j) {
            int n = n0 + quad * 4 + j;
            if (n < NN) dst[(size_t)n * NJ] = f2bf(acc[ct][j]);
        }
    }
}

// ---------------------------------------------------------------------------
// Kernel E: epilogue
// pre[j] = sum_d E[n,d]*G0[b,n,dj] + (1/sum_s rsum[s][n]) * sum_d E[n,d]*PGsum + bias
// R=sigmoid(pre[0..1]), C=tanh(pre[2..3]), h=(1-R)*C, y = relu(h)@lin_w + lin_b
// ---------------------------------------------------------------------------
__global__ __launch_bounds__(256)
void ke_out(const float* __restrict__ e, const float* __restrict__ rsum,
            const float* __restrict__ g0, const ushort* __restrict__ pgu,
            const float* __restrict__ bg, const float* __restrict__ bu,
            const float* __restrict__ lw, const float* __restrict__ lb,
            float* __restrict__ out) {
    int n = blockIdx.x * 256 + threadIdx.x;
    int b = blockIdx.y;
    if (n >= NN) return;
    const float4* E4 = (const float4*)e;
    float4 ev = E4[n];
    float ed[4] = {ev.x, ev.y, ev.z, ev.w};
    float den = 0.f;
    #pragma unroll
    for (int s = 0; s < OUTER; ++s) den += rsum[(size_t)s * MPAD + n];
    float rd = 1.f / den;
    size_t base = ((size_t)b * NN + n) * NJ;

    float g0f[16];
    #pragma unroll
    for (int i = 0; i < 4; ++i) {
        float4 t = *(const float4*)(g0 + base + i * 4);
        g0f[i*4+0] = t.x; g0f[i*4+1] = t.y; g0f[i*4+2] = t.z; g0f[i*4+3] = t.w;
    }
    float pgf[16];
    #pragma unroll
    for (int i = 0; i < 16; ++i) pgf[i] = 0.f;
    #pragma unroll
    for (int s = 0; s < OUTER; ++s) {
        const ushort* sp = pgu + (size_t)s * BB * NN * NJ + base;
        #pragma unroll
        for (int i = 0; i < 16; ++i) {
            uint u = (uint)sp[i] << 16;
            pgf[i] += __uint_as_float(u);
        }
    }

    float pre[4];
    #pragma unroll
    for (int j = 0; j < 4; ++j) {
        float t0 = 0.f, t1 = 0.f, bj = 0.f;
        #pragma unroll
        for (int d = 0; d < 4; ++d) {
            t0 += ed[d] * g0f[d*4+j];
            t1 += ed[d] * pgf[d*4+j];
            float bp = (j < 2) ? bg[d * 4 + 2 + j] : bu[d * 2 + (j - 2)];
            bj += ed[d] * bp;
        }
        pre[j] = t0 + rd * t1 + bj;
    }
    float R0 = 1.f / (1.f + __expf(-pre[0]));
    float R1 = 1.f / (1.f + __expf(-pre[1]));
    float C0 = tanhf(pre[2]);
    float C1 = tanhf(pre[3]);
    float h0 = (1.f - R0) * C0;
    float h1 = (1.f - R1) * C1;
    float y = fmaxf(h0, 0.f) * lw[0] + fmaxf(h1, 0.f) * lw[1] + lb[0];
    out[(size_t)b * NN + n] = y;
}

// ---------------------------------------------------------------------------
extern "C" void kernel_launch(void* const* d_in, const int* in_sizes, int n_in,
                              void* d_out, int out_size, void* d_ws, size_t ws_size,
                              hipStream_t stream) {
    const float* x  = (const float*)d_in[0];
    const float* e  = (const float*)d_in[1];
    const float* wg = (const float*)d_in[2];
    const float* bg = (const float*)d_in[3];
    const float* wu = (const float*)d_in[4];
    const float* bu = (const float*)d_in[5];
    const float* lw = (const float*)d_in[6];
    const float* lb = (const float*)d_in[7];
    float* out = (float*)d_out;

    float*  wsf  = (float*)d_ws;
    float*  rsum = wsf + OFF_RSUM;
    float*  g0   = wsf + OFF_G0;
    ushort* pgu  = (ushort*)(wsf + OFF_PGU);
    ushort* gtu  = (ushort*)(wsf + OFF_GT);

    hipLaunchKernelGGL(kg_g, dim3(22, 16), dim3(256), 0, stream, x, wg, wu, g0, gtu);
    hipLaunchKernelGGL(kb_pg, dim3(MPAD / 64, OUTER), dim3(256), 0, stream, e, gtu, pgu, rsum);
    hipLaunchKernelGGL(ke_out, dim3(22, 16), dim3(256), 0, stream,
                       e, rsum, g0, pgu, bg, bu, lw, lb, out);
}

// Round 4
// 217.018 us; speedup vs baseline: 1.1042x; 1.1042x over previous
//
#include <hip/hip_runtime.h>
#include <hip/hip_bf16.h>
#include <math.h>

// Problem constants (fixed by setup_inputs)
#define NN   5570
#define BB   16
#define CIN  35
#define NJ   16        // (d,j): d in [0,4), j in [0,4) (j: gate-o2, gate-o3, upd-o0, upd-o1)
#define MPAD 5632      // NN padded to 88*64
#define NCHUNK 176     // MPAD/32
#define OUTER 8        // split-K slices
#define KW   704       // MPAD/OUTER, 22 steps of 32

// workspace layout (float offsets); total = 7,895,552 floats = 31.6 MB
#define OFF_RSUM 0                                          // [OUTER][MPAD] fp32
#define OFF_G0   45056                                      // [BB][NN][NJ] fp32
#define OFF_PGU  1470976                                    // [OUTER][BB][NN][NJ] bf16
#define OFF_GT   7174656                                    // gtf bf16 [NCHUNK][BB][64][8]

typedef __attribute__((ext_vector_type(8))) short  short8;
typedef __attribute__((ext_vector_type(4))) float  floatx4;

static __device__ inline ushort f2bf(float f) {
    union { __hip_bfloat16 h; ushort u; } cv;
    cv.h = __float2bfloat16(f);
    return cv.u;
}

// ---------------------------------------------------------------------------
// Kernel G: per (b, m):
//   a0[dj] = sum_c x[b,m,c] * w_k0[d,c,j]  -> g0  fp32 [b][m][16]
//   a1[dj] = sum_c x[b,m,c] * w_k1[d,c,j]  -> gtf bf16, MFMA-B-fragment order:
//       gtf[((chunk*16 + b)*64 + quad*16 + dj)*8 + u]  where
//       chunk=m>>5, quad=(m>>3)&3, u=m&7   (lane=quad*16+l15 holds B[k][col=b*16+l15])
// tail m in [NN, MPAD): gtf <- 0
// ---------------------------------------------------------------------------
__global__ __launch_bounds__(256)
void kg_g(const float* __restrict__ x, const float* __restrict__ wg,
          const float* __restrict__ wu, float* __restrict__ g0,
          ushort* __restrict__ gtf) {
    __shared__ float xs[256 * CIN];
    __shared__ float wl[8 * CIN * 4];   // [(k*4+d)*35 + c]*4 + j
    int tid = threadIdx.x;
    int b   = blockIdx.y;
    int m0  = blockIdx.x * 256;

    for (int i = tid; i < 8 * CIN * 4; i += 256) {
        int j = i & 3, rest = i >> 2;
        int c = rest % CIN, kd = rest / CIN;
        int k = kd >> 2, d = kd & 3;
        float v;
        if (j < 2) v = wg[((d * 2 + k) * 37 + c) * 4 + 2 + j];
        else       v = wu[((d * 2 + k) * 37 + c) * 2 + (j - 2)];
        wl[i] = v;
    }
    int rows = NN - m0; if (rows > 256) rows = 256; if (rows < 0) rows = 0;
    const float* xsrc = x + ((size_t)b * NN + m0) * CIN;
    for (int i = tid; i < rows * CIN; i += 256) xs[i] = xsrc[i];
    __syncthreads();

    int m = m0 + tid;
    const int chunk = m >> 5, quad = (m >> 3) & 3, u = m & 7;
    ushort* gdst = gtf + (((size_t)chunk * 16 + b) * 64 + quad * 16) * 8 + u;

    if (m < NN) {
        float a0[16], a1[16];
        #pragma unroll
        for (int i = 0; i < 16; ++i) { a0[i] = 0.f; a1[i] = 0.f; }
        for (int c = 0; c < CIN; ++c) {
            float xa = xs[tid * CIN + c];
            #pragma unroll
            for (int kd = 0; kd < 8; ++kd) {
                const float4 w = *(const float4*)&wl[(kd * CIN + c) * 4];
                const int d4 = (kd & 3) * 4;
                if (kd < 4) {
                    a0[d4+0] += xa*w.x; a0[d4+1] += xa*w.y;
                    a0[d4+2] += xa*w.z; a0[d4+3] += xa*w.w;
                } else {
                    a1[d4+0] += xa*w.x; a1[d4+1] += xa*w.y;
                    a1[d4+2] += xa*w.z; a1[d4+3] += xa*w.w;
                }
            }
        }
        float* p0 = g0 + ((size_t)b * NN + m) * NJ;
        ((float4*)p0)[0] = make_float4(a0[0], a0[1], a0[2], a0[3]);
        ((float4*)p0)[1] = make_float4(a0[4], a0[5], a0[6], a0[7]);
        ((float4*)p0)[2] = make_float4(a0[8], a0[9], a0[10], a0[11]);
        ((float4*)p0)[3] = make_float4(a0[12], a0[13], a0[14], a0[15]);
        #pragma unroll
        for (int dj = 0; dj < 16; ++dj)
            gdst[(size_t)dj * 8] = f2bf(a1[dj]);
    } else {
        #pragma unroll
        for (int dj = 0; dj < 16; ++dj)
            gdst[(size_t)dj * 8] = 0;
    }
}

// ---------------------------------------------------------------------------
// Kernel B (MFMA, barrier-free, zero LDS, coalesced B):
//   PG[s][b][n][dj] = sum_{m in slice s} exp(relu(E_n.E_m)) * G1[m][b*16+dj]
//   rsum[s][n]      = sum_{m in slice s} exp(relu(E_n.E_m))
// Wave w owns rows n0 = bx*64 + w*16 and all 16 col-tiles (ct == batch).
// A-fragment scores computed in-register (lane holds A[n0+l15][quad*8+u]).
// B-fragments: gtf in fragment order -> lane l reads gtf[chunk][ct][l*8..l*8+7],
// i.e. each load is a contiguous 1KB wave transaction; all waves in the block
// read the same 16KB/step (L1 temporal reuse).
// ---------------------------------------------------------------------------
template <bool CHECK>
static __device__ inline void kb_body(const float4* __restrict__ E4,
                                      const ushort* __restrict__ gl,
                                      const float4 en, int k0,
                                      floatx4 (&acc)[16], float& rowsum,
                                      int quad) {
    #pragma unroll 11
    for (int step = 0; step < KW / 32; ++step) {
        const int mq = k0 + step * 32 + quad * 8;
        short8 afrag;
        #pragma unroll
        for (int u = 0; u < 8; ++u) {
            int m = mq + u;
            float4 em = E4[(CHECK && m >= NN) ? 0 : m];
            float dt = en.x*em.x + en.y*em.y + en.z*em.z + en.w*em.w;
            float sv = __expf(fmaxf(dt, 0.f));
            if (CHECK && m >= NN) sv = 0.f;
            rowsum += sv;
            afrag[u] = (short)f2bf(sv);
        }
        const ushort* gs = gl + ((size_t)((k0 >> 5) + step) << 13);
        #pragma unroll
        for (int ct = 0; ct < 16; ++ct) {
            short8 bf = *(const short8*)&gs[ct * 512];
            acc[ct] = __builtin_amdgcn_mfma_f32_16x16x32_bf16(afrag, bf, acc[ct], 0, 0, 0);
        }
    }
}

__global__ __launch_bounds__(256)
void kb_pg(const float* __restrict__ e, const ushort* __restrict__ gtf,
           ushort* __restrict__ pgu, float* __restrict__ rsum) {
    const int tid  = threadIdx.x;
    const int wave = tid >> 6;
    const int lane = tid & 63;
    const int l15  = lane & 15;
    const int quad = lane >> 4;
    const int n0   = blockIdx.x * 64 + wave * 16;
    const int s    = blockIdx.y;
    const int k0   = s * KW;
    const float4* E4 = (const float4*)e;

    const int nr = n0 + l15;
    const float4 en = E4[nr < NN ? nr : 0];

    floatx4 acc[16];
    #pragma unroll
    for (int i = 0; i < 16; ++i) acc[i] = (floatx4){0.f, 0.f, 0.f, 0.f};
    float rowsum = 0.f;

    const ushort* gl = gtf + (size_t)lane * 8;

    if (k0 + KW <= NN) kb_body<false>(E4, gl, en, k0, acc, rowsum, quad);
    else               kb_body<true >(E4, gl, en, k0, acc, rowsum, quad);

    // rowsum for row nr lives in lanes {l15, l15+16, l15+32, l15+48}
    rowsum += __shfl_xor(rowsum, 16);
    rowsum += __shfl_xor(rowsum, 32);
    if (quad == 0 && nr < NN) rsum[(size_t)s * MPAD + nr] = rowsum;

    // store PG bf16: D[row = quad*4 + j][col = l15]; col-tile ct == batch index
    #pragma unroll
    for (int ct = 0; ct < 16; ++ct) {
        ushort* dst = pgu + ((size_t)s * BB + ct) * NN * NJ + l15;
        #pragma unroll
        for (int j = 0; j < 4; ++j) {
            int n = n0 + quad * 4 + j;
            if (n < NN) dst[(size_t)n * NJ] = f2bf(acc[ct][j]);
        }
    }
}

// ---------------------------------------------------------------------------
// Kernel E: epilogue (vectorized loads)
// pre[j] = sum_d E[n,d]*G0[b,n,dj] + (1/sum_s rsum[s][n]) * sum_d E[n,d]*PGsum + bias
// R=sigmoid(pre[0..1]), C=tanh(pre[2..3]), h=(1-R)*C, y = relu(h)@lin_w + lin_b
// ---------------------------------------------------------------------------
__global__ __launch_bounds__(256)
void ke_out(const float* __restrict__ e, const float* __restrict__ rsum,
            const float* __restrict__ g0, const ushort* __restrict__ pgu,
            const float* __restrict__ bg, const float* __restrict__ bu,
            const float* __restrict__ lw, const float* __restrict__ lb,
            float* __restrict__ out) {
    int n = blockIdx.x * 256 + threadIdx.x;
    int b = blockIdx.y;
    if (n >= NN) return;
    const float4* E4 = (const float4*)e;
    float4 ev = E4[n];
    float ed[4] = {ev.x, ev.y, ev.z, ev.w};
    float den = 0.f;
    #pragma unroll
    for (int s = 0; s < OUTER; ++s) den += rsum[(size_t)s * MPAD + n];
    float rd = 1.f / den;
    size_t base = ((size_t)b * NN + n) * NJ;

    float g0f[16];
    #pragma unroll
    for (int i = 0; i < 4; ++i) {
        float4 t = *(const float4*)(g0 + base + i * 4);
        g0f[i*4+0] = t.x; g0f[i*4+1] = t.y; g0f[i*4+2] = t.z; g0f[i*4+3] = t.w;
    }
    float pgf[16];
    #pragma unroll
    for (int i = 0; i < 16; ++i) pgf[i] = 0.f;
    #pragma unroll
    for (int s = 0; s < OUTER; ++s) {
        const uint4* sp = (const uint4*)(pgu + (size_t)s * BB * NN * NJ + base);
        uint4 p0 = sp[0], p1 = sp[1];
        uint w8[8] = {p0.x, p0.y, p0.z, p0.w, p1.x, p1.y, p1.z, p1.w};
        #pragma unroll
        for (int i = 0; i < 8; ++i) {
            pgf[2*i]   += __uint_as_float(w8[i] << 16);
            pgf[2*i+1] += __uint_as_float(w8[i] & 0xffff0000u);
        }
    }

    float pre[4];
    #pragma unroll
    for (int j = 0; j < 4; ++j) {
        float t0 = 0.f, t1 = 0.f, bj = 0.f;
        #pragma unroll
        for (int d = 0; d < 4; ++d) {
            t0 += ed[d] * g0f[d*4+j];
            t1 += ed[d] * pgf[d*4+j];
            float bp = (j < 2) ? bg[d * 4 + 2 + j] : bu[d * 2 + (j - 2)];
            bj += ed[d] * bp;
        }
        pre[j] = t0 + rd * t1 + bj;
    }
    float R0 = 1.f / (1.f + __expf(-pre[0]));
    float R1 = 1.f / (1.f + __expf(-pre[1]));
    float C0 = tanhf(pre[2]);
    float C1 = tanhf(pre[3]);
    float h0 = (1.f - R0) * C0;
    float h1 = (1.f - R1) * C1;
    float y = fmaxf(h0, 0.f) * lw[0] + fmaxf(h1, 0.f) * lw[1] + lb[0];
    out[(size_t)b * NN + n] = y;
}

// ---------------------------------------------------------------------------
extern "C" void kernel_launch(void* const* d_in, const int* in_sizes, int n_in,
                              void* d_out, int out_size, void* d_ws, size_t ws_size,
                              hipStream_t stream) {
    const float* x  = (const float*)d_in[0];
    const float* e  = (const float*)d_in[1];
    const float* wg = (const float*)d_in[2];
    const float* bg = (const float*)d_in[3];
    const float* wu = (const float*)d_in[4];
    const float* bu = (const float*)d_in[5];
    const float* lw = (const float*)d_in[6];
    const float* lb = (const float*)d_in[7];
    float* out = (float*)d_out;

    float*  wsf  = (float*)d_ws;
    float*  rsum = wsf + OFF_RSUM;
    float*  g0   = wsf + OFF_G0;
    ushort* pgu  = (ushort*)(wsf + OFF_PGU);
    ushort* gtf  = (ushort*)(wsf + OFF_GT);

    hipLaunchKernelGGL(kg_g, dim3(22, 16), dim3(256), 0, stream, x, wg, wu, g0, gtf);
    hipLaunchKernelGGL(kb_pg, dim3(MPAD / 64, OUTER), dim3(256), 0, stream, e, gtf, pgu, rsum);
    hipLaunchKernelGGL(ke_out, dim3(22, 16), dim3(256), 0, stream,
                       e, rsum, g0, pgu, bg, bu, lw, lb, out);
}